// Round 14
// baseline (2714.221 us; speedup 1.0000x reference)
//
#include <hip/hip_runtime.h>
#include <math.h>
#include <float.h>

constexpr int NE   = 64;      // experts
constexpr int ND   = 2048;    // hidden dim
constexpr int TOPK = 8;
constexpr int NWV  = 8;       // waves per block
constexpr int BLK  = NWV * 64;// 512 threads
constexpr int EPW  = NE / NWV;// 8 experts per wave
constexpr int KC   = 64;      // k-chunk
constexpr int NCH  = ND / KC; // 32 chunks
constexpr int HB   = 0;       // smem float offset: h tiles, 2 x 4096
constexpr int WB   = 8192;    // smem float offset: w tiles, 2 x 4096

// Numerics contract (DO NOT CHANGE — validated in round 11):
// h @ w.T emulating OpenBLAS sgemm fp32: K=2048 in kc panels
// {384,384,384,384,256,256}; per C-element per panel ONE accumulator,
// serial fp32 FMA with k strictly ascending; panel sums added to C in
// order (__fadd_rn). Then np ufuncs: l = fadd(fmul(raw, cs), cb), fp32,
// unfused. Rank on l32, ties -> lower index. Softmax value outputs fp32.
__global__ __launch_bounds__(BLK, 2)
void gate_kernel(const float* __restrict__ h, const float* __restrict__ w,
                 const float* __restrict__ cs, const float* __restrict__ cb,
                 float* __restrict__ out, int T)
{
    __shared__ float smem[16384];   // 64 KB: hb 2x4096 | wb 2x4096

    const int tid  = threadIdx.x;
    const int lane = tid & 63;                       // lane = token
    const int wv   = __builtin_amdgcn_readfirstlane(tid >> 6);
    const int t0   = blockIdx.x * 64;

    // staging roles: 8 threads per row, 8-float segment each
    const int srow = tid >> 3;       // 0..63 (token row for h, expert row for w)
    const int sseg = tid & 7;        // segment
    const float* hsrc = h + (size_t)(t0 + srow) * ND + sseg * 8;
    const float* wsrc = w + (size_t)srow * ND + sseg * 8;
    const int hslot0 = (2 * sseg)     ^ (srow & 15); // XOR slot swizzle (4-float slots)
    const int hslot1 = (2 * sseg + 1) ^ (srow & 15);

    float C[EPW], a[EPW];
#pragma unroll
    for (int i = 0; i < EPW; ++i) C[i] = 0.f;

    // prologue: stage chunk 0 into buffer 0
    {
        const float4 h0 = *reinterpret_cast<const float4*>(hsrc);
        const float4 h1 = *reinterpret_cast<const float4*>(hsrc + 4);
        const float4 w0 = *reinterpret_cast<const float4*>(wsrc);
        const float4 w1 = *reinterpret_cast<const float4*>(wsrc + 4);
        *reinterpret_cast<float4*>(&smem[HB + srow * 64 + hslot0 * 4]) = h0;
        *reinterpret_cast<float4*>(&smem[HB + srow * 64 + hslot1 * 4]) = h1;
        *reinterpret_cast<float4*>(&smem[WB + srow * 64 + sseg * 8])     = w0;
        *reinterpret_cast<float4*>(&smem[WB + srow * 64 + sseg * 8 + 4]) = w1;
    }
    __syncthreads();

#pragma unroll 1
    for (int c = 0; c < NCH; ++c) {
        const int buf = c & 1;
        // panel boundaries (k multiples of 64): starts c={0,6,12,18,24,28}
        const bool pstart = (c == 0) || (c == 6) || (c == 12) || (c == 18) || (c == 24) || (c == 28);
        const bool pend   = (c == 5) || (c == 11) || (c == 17) || (c == 23) || (c == 27) || (c == 31);
        if (pstart) {
#pragma unroll
            for (int i = 0; i < EPW; ++i) a[i] = 0.f;
        }

        // prefetch next chunk (global -> regs), overlaps with compute below
        float4 nh0, nh1, nw0, nw1;
        if (c + 1 < NCH) {
            const int kn = (c + 1) * KC;
            nh0 = *reinterpret_cast<const float4*>(hsrc + kn);
            nh1 = *reinterpret_cast<const float4*>(hsrc + kn + 4);
            nw0 = *reinterpret_cast<const float4*>(wsrc + kn);
            nw1 = *reinterpret_cast<const float4*>(wsrc + kn + 4);
        }

        // ---- compute chunk c: serial FMA, k ascending (contract) ----
        const float* hbp = &smem[HB + buf * 4096 + lane * 64];
        const float* wbp = &smem[WB + buf * 4096 + wv * EPW * 64];
#pragma unroll
        for (int k4 = 0; k4 < KC / 4; ++k4) {
            const float4 h4 = *reinterpret_cast<const float4*>(
                                  hbp + ((k4 ^ (lane & 15)) * 4));   // conflict-free
#pragma unroll
            for (int i = 0; i < EPW; ++i) {
                const float4 w4 = *reinterpret_cast<const float4*>(
                                      wbp + i * 64 + k4 * 4);        // wave broadcast
                float t = a[i];
                t = __builtin_fmaf(h4.x, w4.x, t);
                t = __builtin_fmaf(h4.y, w4.y, t);
                t = __builtin_fmaf(h4.z, w4.z, t);
                t = __builtin_fmaf(h4.w, w4.w, t);
                a[i] = t;
            }
        }

        if (pend) {
#pragma unroll
            for (int i = 0; i < EPW; ++i) C[i] = __fadd_rn(C[i], a[i]);
        }

        __syncthreads();
        if (c + 1 < NCH) {
            const int nb = (c + 1) & 1;
            *reinterpret_cast<float4*>(&smem[HB + nb * 4096 + srow * 64 + hslot0 * 4]) = nh0;
            *reinterpret_cast<float4*>(&smem[HB + nb * 4096 + srow * 64 + hslot1 * 4]) = nh1;
            *reinterpret_cast<float4*>(&smem[WB + nb * 4096 + srow * 64 + sseg * 8])     = nw0;
            *reinterpret_cast<float4*>(&smem[WB + nb * 4096 + srow * 64 + sseg * 8 + 4]) = nw1;
        }
        __syncthreads();
    }

    // ---- epilogue (validated in R11): alias LDS after final barrier ----
    float* const sl   = smem;           // [e][t] logits, 4096
    float* const pp   = smem + 4096;    // [t][e] swizzled unnorm probs, 4096
    float* const pinv = smem + 8192;    // 64

#pragma unroll
    for (int i = 0; i < EPW; ++i) {
        const int e = wv * EPW + i;
        // np ufuncs: mul then add, both rounded fp32, no fma contraction
        sl[e * 64 + lane] = __fadd_rn(__fmul_rn(C[i], cs[e]), cb[e]);
    }
    __syncthreads();

    float* const out_probs = out;                           // T*64
    float* const out_wts   = out + (size_t)T * NE;          // T*8
    float* const out_idx   = out + (size_t)T * (NE + TOPK); // T*8

    if (wv == 0) {
        float l[NE];
#pragma unroll
        for (int e = 0; e < NE; ++e) l[e] = sl[e * 64 + lane];

        float m = l[0];
#pragma unroll
        for (int e = 1; e < NE; ++e) m = fmaxf(m, l[e]);

        float u[NE];
        float s = 0.f;
#pragma unroll
        for (int e = 0; e < NE; ++e) {
            u[e] = expf(l[e] - m);
            s += u[e];
        }
        const float inv = 1.f / s;
        pinv[lane] = inv;

#pragma unroll
        for (int e = 0; e < NE; ++e)
            pp[lane * NE + (e ^ (lane & 31))] = u[e];

        // top-8 on l32; strict > insertion, e ascending => ties keep lower index
        float kv[TOPK]; int iv[TOPK];
#pragma unroll
        for (int j = 0; j < TOPK; ++j) { kv[j] = -FLT_MAX; iv[j] = 0; }
#pragma unroll
        for (int e = 0; e < NE; ++e) {
            float v = l[e]; int ix = e;
#pragma unroll
            for (int j = 0; j < TOPK; ++j) {
                const bool gt = v > kv[j];
                const float nv = gt ? kv[j] : v;
                const int   ni = gt ? iv[j] : ix;
                kv[j] = gt ? v  : kv[j];
                iv[j] = gt ? ix : iv[j];
                v = nv; ix = ni;
            }
        }

        float ws0[TOPK];
#pragma unroll
        for (int j = 0; j < TOPK; ++j)
            ws0[j] = pp[lane * NE + (iv[j] ^ (lane & 31))] * inv;

        const int tok = t0 + lane;
        *reinterpret_cast<float4*>(out_wts + (size_t)tok * TOPK)
            = make_float4(ws0[0], ws0[1], ws0[2], ws0[3]);
        *reinterpret_cast<float4*>(out_wts + (size_t)tok * TOPK + 4)
            = make_float4(ws0[4], ws0[5], ws0[6], ws0[7]);
        *reinterpret_cast<float4*>(out_idx + (size_t)tok * TOPK)
            = make_float4((float)iv[0], (float)iv[1], (float)iv[2], (float)iv[3]);
        *reinterpret_cast<float4*>(out_idx + (size_t)tok * TOPK + 4)
            = make_float4((float)iv[4], (float)iv[5], (float)iv[6], (float)iv[7]);
    }
    __syncthreads();

    // cooperative coalesced probs store: 4096 floats / 512 threads = 8 each
    {
        const size_t base = (size_t)t0 * NE;
#pragma unroll
        for (int r = 0; r < (64 * NE) / BLK; ++r) {
            const int idx = r * BLK + tid;
            const int t = idx >> 6, e = idx & 63;
            out_probs[base + idx] = pp[t * NE + (e ^ (t & 31))] * pinv[t];
        }
    }
}

extern "C" void kernel_launch(void* const* d_in, const int* in_sizes, int n_in,
                              void* d_out, int out_size, void* d_ws, size_t ws_size,
                              hipStream_t stream)
{
    const float* h  = (const float*)d_in[0];
    const float* w  = (const float*)d_in[1];
    const float* cs = (const float*)d_in[2];
    const float* cb = (const float*)d_in[3];
    float* outp = (float*)d_out;
    const int T = in_sizes[0] / ND;   // 16384 tokens

    dim3 grid(T / 64);                // 256 blocks (1 per CU)
    dim3 block(BLK);                  // 512 threads, 8 waves
    hipLaunchKernelGGL(gate_kernel, grid, block, 0, stream,
                       h, w, cs, cb, outp, T);
}